// Round 2
// baseline (285.184 us; speedup 1.0000x reference)
//
#include <hip/hip_runtime.h>
#include <hip/hip_bf16.h>

typedef __bf16 bf16x8 __attribute__((ext_vector_type(8)));
typedef float  f32x4  __attribute__((ext_vector_type(4)));

#define N_WORDS   8192
#define CHAR_LEN  16
#define WORD_DIM  300
#define CHAR_DIM  64
#define HID       128
#define G4        512      // 4*HID
#define INFO      556
#define KPAD      576      // 556 padded to 18*32
#define OUTD      512
#define WB        16       // words per block (M tile)

__device__ __forceinline__ float sigmoidf_(float x) {
    return 1.0f / (1.0f + __expf(-x));
}
__device__ __forceinline__ float tanhf_(float x) {
    float a = fabsf(x);
    float e = __expf(2.0f * a);
    float t = 1.0f - 2.0f / (e + 1.0f);   // safe at e=inf -> 1
    return copysignf(t, x);
}

// K1: pre[dir][cid][g] = sum_d char_table[cid][d]*Wih[g][d] + bih[g] + bhh[g]  (fp32 exact)
__global__ void pre_kernel(const float* __restrict__ char_table,
                           const float* __restrict__ Wih_f, const float* __restrict__ bih_f,
                           const float* __restrict__ bhh_f,
                           const float* __restrict__ Wih_b, const float* __restrict__ bih_b,
                           const float* __restrict__ bhh_b,
                           float* __restrict__ pre) {
    const int dir = blockIdx.y;
    const int cid = blockIdx.x;
    const float* Wih = dir ? Wih_b : Wih_f;
    const float* b1  = dir ? bih_b : bih_f;
    const float* b2  = dir ? bhh_b : bhh_f;
    __shared__ float x[CHAR_DIM];
    if (threadIdx.x < CHAR_DIM) x[threadIdx.x] = char_table[cid * CHAR_DIM + threadIdx.x];
    __syncthreads();
    for (int g = threadIdx.x; g < G4; g += 256) {
        float s = b1[g] + b2[g];
        #pragma unroll 8
        for (int d = 0; d < CHAR_DIM; ++d) s += x[d] * Wih[g * CHAR_DIM + d];
        pre[(dir * 128 + cid) * G4 + g] = s;
    }
}

// K0: build bf16 Wpad [512][576] (zero tail) and bf16 Whh [2][512][128] from fp32 inputs
__global__ void prep_kernel(const float* __restrict__ W_out,
                            const float* __restrict__ Whh_f, const float* __restrict__ Whh_b,
                            __bf16* __restrict__ Wpad, __bf16* __restrict__ WhhB) {
    int idx = blockIdx.x * 256 + threadIdx.x;
    if (idx < OUTD * KPAD) {
        int row = idx / KPAD, col = idx - row * KPAD;
        Wpad[idx] = (col < INFO) ? (__bf16)W_out[row * INFO + col] : (__bf16)0.0f;
    } else {
        int j = idx - OUTD * KPAD;
        if (j < 2 * G4 * HID) {
            const float* src = (j < G4 * HID) ? Whh_f : Whh_b;
            int k = (j < G4 * HID) ? j : j - G4 * HID;
            WhhB[j] = (__bf16)src[k];
        }
    }
}

// K2: persistent BiLSTM recurrence. Block: 16 words x 1 direction, 256 thr (4 waves).
// Wave w owns hidden slice j in [w*32, w*32+32) for ALL four gates -> local c/h update.
__global__ __launch_bounds__(256) void lstm_kernel(
        const int*   __restrict__ char_ids,   // [8192][16] int32
        const float* __restrict__ pre,        // [2][128][512] fp32
        const __bf16* __restrict__ WhhB,      // [2][512][128] bf16 (from prep)
        __bf16* __restrict__ char_feat) {     // [8192][256] bf16
    const int dir = blockIdx.y;
    const int wb  = blockIdx.x * WB;
    const __bf16* Whh = WhhB + dir * G4 * HID;
    const float* preD = pre + dir * 128 * G4;

    const int tid  = threadIdx.x;
    const int wave = tid >> 6;
    const int lane = tid & 63;
    const int col  = lane & 15;   // n-index within 16-wide tile / m for A reads
    const int quad = lane >> 4;

    __shared__ __bf16 h_lds[WB][136];   // pad 128->136: 272B row stride, 16B aligned, 2-way banks
    __shared__ int    cid_lds[WB][CHAR_LEN];

    if (tid < WB * CHAR_LEN) {
        int w = tid >> 4, t = tid & 15;
        cid_lds[w][t] = char_ids[(wb + w) * CHAR_LEN + t];
    }
    for (int i = tid; i < WB * 136; i += 256) ((__bf16*)h_lds)[i] = (__bf16)0.0f;

    // Hoist Whh B-fragments into registers, reused all 16 timesteps.
    // B[k][n] = Whh[n][k]; lane holds n = jbase+jt*16+col, k = ks*32 + quad*8 + j.
    const int jbase = wave * 32;
    bf16x8 Bfrag[4][2][4];   // [gate type][jt][kstep]
    #pragma unroll
    for (int tt = 0; tt < 4; ++tt)
        #pragma unroll
        for (int jt = 0; jt < 2; ++jt) {
            int row = tt * HID + jbase + jt * 16 + col;   // gate column = Whh row
            #pragma unroll
            for (int ks = 0; ks < 4; ++ks)
                Bfrag[tt][jt][ks] = *(const bf16x8*)(Whh + row * HID + ks * 32 + quad * 8);
        }

    float c[2][4]    = {};
    float sumh[2][4] = {};
    __syncthreads();

    for (int t = 0; t < CHAR_LEN; ++t) {
        const int tc = dir ? (CHAR_LEN - 1 - t) : t;

        // acc init = input-projection gather (includes both biases)
        f32x4 acc[4][2];
        #pragma unroll
        for (int r = 0; r < 4; ++r) {
            int wrow = quad * 4 + r;
            const float* p = preD + cid_lds[wrow][tc] * G4;
            #pragma unroll
            for (int tt = 0; tt < 4; ++tt)
                #pragma unroll
                for (int jt = 0; jt < 2; ++jt)
                    acc[tt][jt][r] = p[tt * HID + jbase + jt * 16 + col];
        }

        // A fragments: A[m][k] = h[m][k], m = col, k = ks*32 + quad*8 + j
        bf16x8 Afrag[4];
        #pragma unroll
        for (int ks = 0; ks < 4; ++ks)
            Afrag[ks] = *(const bf16x8*)(&h_lds[col][ks * 32 + quad * 8]);
        __syncthreads();   // all reads of old h done before anyone writes new h

        #pragma unroll
        for (int tt = 0; tt < 4; ++tt)
            #pragma unroll
            for (int jt = 0; jt < 2; ++jt)
                #pragma unroll
                for (int ks = 0; ks < 4; ++ks)
                    acc[tt][jt] = __builtin_amdgcn_mfma_f32_16x16x32_bf16(
                        Afrag[ks], Bfrag[tt][jt][ks], acc[tt][jt], 0, 0, 0);

        // gate order i,f,g,o ; C/D layout: word = quad*4+reg, col = n
        #pragma unroll
        for (int jt = 0; jt < 2; ++jt)
            #pragma unroll
            for (int r = 0; r < 4; ++r) {
                float iv = sigmoidf_(acc[0][jt][r]);
                float fv = sigmoidf_(acc[1][jt][r]);
                float gv = tanhf_  (acc[2][jt][r]);
                float ov = sigmoidf_(acc[3][jt][r]);
                float cv = fv * c[jt][r] + iv * gv;
                c[jt][r] = cv;
                float hv = ov * tanhf_(cv);
                sumh[jt][r] += hv;
                h_lds[quad * 4 + r][jbase + jt * 16 + col] = (__bf16)hv;
            }
        __syncthreads();   // new h visible before next iteration's reads
    }

    #pragma unroll
    for (int jt = 0; jt < 2; ++jt)
        #pragma unroll
        for (int r = 0; r < 4; ++r) {
            int word = wb + quad * 4 + r;
            int j    = jbase + jt * 16 + col;
            char_feat[word * 256 + dir * HID + j] = (__bf16)sumh[jt][r];
        }
}

// K3: out[n][o] = tanh( feat[n] . W_out[o] + b_out[o] ), MFMA over K=576, fp32 out
__global__ __launch_bounds__(256) void out_kernel(
        const int*   __restrict__ word_ids,
        const float* __restrict__ word_table,   // [50000][300] fp32
        const __bf16* __restrict__ char_feat,   // [8192][256] bf16
        const __bf16* __restrict__ Wpad,        // [512][576] bf16
        const float* __restrict__ b_out,        // [512] fp32
        float* __restrict__ out) {              // [8192][512] fp32
    const int wb  = blockIdx.x * WB;
    const int tid = threadIdx.x;
    const int wave = tid >> 6, lane = tid & 63, col = lane & 15, quad = lane >> 4;

    __shared__ __bf16 feat[WB][584];   // 584: 16B-aligned rows, non-pow2 banks
    __shared__ int wid[WB];
    if (tid < WB) wid[tid] = word_ids[wb + tid];
    __syncthreads();
    for (int idx = tid; idx < WB * 584; idx += 256) {
        int row = idx / 584, cc = idx - row * 584;
        __bf16 v;
        if (cc < WORD_DIM)      v = (__bf16)word_table[wid[row] * WORD_DIM + cc];
        else if (cc < INFO)     v = char_feat[(wb + row) * 256 + (cc - WORD_DIM)];
        else                    v = (__bf16)0.0f;
        feat[row][cc] = v;
    }
    __syncthreads();

    f32x4 acc[8];
    #pragma unroll
    for (int i = 0; i < 8; ++i) acc[i] = (f32x4){0.f, 0.f, 0.f, 0.f};

    for (int kb = 0; kb < KPAD / 32; ++kb) {
        bf16x8 A = *(const bf16x8*)(&feat[col][kb * 32 + quad * 8]);
        #pragma unroll
        for (int nt = 0; nt < 8; ++nt) {
            int n = wave * 128 + nt * 16 + col;
            bf16x8 B = *(const bf16x8*)(Wpad + n * KPAD + kb * 32 + quad * 8);
            acc[nt] = __builtin_amdgcn_mfma_f32_16x16x32_bf16(A, B, acc[nt], 0, 0, 0);
        }
    }

    #pragma unroll
    for (int nt = 0; nt < 8; ++nt) {
        int n = wave * 128 + nt * 16 + col;
        float bo = b_out[n];
        #pragma unroll
        for (int r = 0; r < 4; ++r) {
            int word = wb + quad * 4 + r;
            out[word * OUTD + n] = tanhf_(acc[nt][r] + bo);
        }
    }
}

extern "C" void kernel_launch(void* const* d_in, const int* in_sizes, int n_in,
                              void* d_out, int out_size, void* d_ws, size_t ws_size,
                              hipStream_t stream) {
    const int*   word_ids   = (const int*)d_in[0];
    const int*   char_ids   = (const int*)d_in[1];
    const float* word_table = (const float*)d_in[2];
    const float* char_table = (const float*)d_in[3];
    const float* Wih_f = (const float*)d_in[4];
    const float* Whh_f = (const float*)d_in[5];
    const float* bih_f = (const float*)d_in[6];
    const float* bhh_f = (const float*)d_in[7];
    const float* Wih_b = (const float*)d_in[8];
    const float* Whh_b = (const float*)d_in[9];
    const float* bih_b = (const float*)d_in[10];
    const float* bhh_b = (const float*)d_in[11];
    const float* W_out = (const float*)d_in[12];
    const float* b_out = (const float*)d_in[13];

    char* ws = (char*)d_ws;
    float*  pre       = (float*)ws;                         // 2*128*512*4 = 512 KB
    __bf16* WhhB      = (__bf16*)(ws + 524288);             // 2*512*128*2 = 256 KB
    __bf16* Wpad      = (__bf16*)(ws + 524288 + 262144);    // 512*576*2   = 576 KB
    __bf16* char_feat = (__bf16*)(ws + 524288 + 262144 + 589824);  // 8192*256*2 = 4 MB

    prep_kernel<<<(OUTD * KPAD + 2 * G4 * HID + 255) / 256, 256, 0, stream>>>(
        W_out, Whh_f, Whh_b, Wpad, WhhB);
    pre_kernel<<<dim3(128, 2), 256, 0, stream>>>(char_table, Wih_f, bih_f, bhh_f,
                                                 Wih_b, bih_b, bhh_b, pre);
    lstm_kernel<<<dim3(N_WORDS / WB, 2), 256, 0, stream>>>(char_ids, pre, WhhB, char_feat);
    out_kernel<<<N_WORDS / WB, 256, 0, stream>>>(word_ids, word_table, char_feat, Wpad, b_out,
                                                 (float*)d_out);
}

// Round 3
// 283.866 us; speedup vs baseline: 1.0046x; 1.0046x over previous
//
#include <hip/hip_runtime.h>
#include <hip/hip_bf16.h>

typedef __bf16 bf16x8 __attribute__((ext_vector_type(8)));
typedef float  f32x4  __attribute__((ext_vector_type(4)));
typedef float  f32x4v __attribute__((ext_vector_type(4)));

#define N_WORDS   8192
#define CHAR_LEN  16
#define WORD_DIM  300
#define CHAR_DIM  64
#define HID       128
#define G4        512      // 4*HID
#define INFO      556
#define KPAD      576      // 556 padded to 18*32
#define OUTD      512
#define WB        16       // words per lstm block (M tile)
#define WB2       32       // words per out block

__device__ __forceinline__ float sigmoidf_(float x) {
    return 1.0f / (1.0f + __expf(-x));
}
__device__ __forceinline__ float tanhf_(float x) {
    float a = fabsf(x);
    float e = __expf(2.0f * a);
    float t = 1.0f - 2.0f / (e + 1.0f);   // safe at e=inf -> 1
    return copysignf(t, x);
}

// K1: pre[dir][cid][g] = sum_d char_table[cid][d]*Wih[g][d] + bih[g] + bhh[g]  (fp32 exact)
__global__ void pre_kernel(const float* __restrict__ char_table,
                           const float* __restrict__ Wih_f, const float* __restrict__ bih_f,
                           const float* __restrict__ bhh_f,
                           const float* __restrict__ Wih_b, const float* __restrict__ bih_b,
                           const float* __restrict__ bhh_b,
                           float* __restrict__ pre) {
    const int dir = blockIdx.y;
    const int cid = blockIdx.x;
    const float* Wih = dir ? Wih_b : Wih_f;
    const float* b1  = dir ? bih_b : bih_f;
    const float* b2  = dir ? bhh_b : bhh_f;
    __shared__ float x[CHAR_DIM];
    if (threadIdx.x < CHAR_DIM) x[threadIdx.x] = char_table[cid * CHAR_DIM + threadIdx.x];
    __syncthreads();
    for (int g = threadIdx.x; g < G4; g += 256) {
        const f32x4v* w4 = (const f32x4v*)(Wih + g * CHAR_DIM);
        const f32x4v* x4 = (const f32x4v*)x;
        float s = b1[g] + b2[g];
        #pragma unroll
        for (int d = 0; d < CHAR_DIM / 4; ++d) {
            f32x4v wv = w4[d], xv = x4[d];
            s += wv[0]*xv[0] + wv[1]*xv[1] + wv[2]*xv[2] + wv[3]*xv[3];
        }
        pre[(dir * 128 + cid) * G4 + g] = s;
    }
}

// K0: build bf16 Wpad [512][576] (zero tail) and bf16 Whh [2][512][128] from fp32 inputs
__global__ void prep_kernel(const float* __restrict__ W_out,
                            const float* __restrict__ Whh_f, const float* __restrict__ Whh_b,
                            __bf16* __restrict__ Wpad, __bf16* __restrict__ WhhB) {
    int idx = blockIdx.x * 256 + threadIdx.x;
    if (idx < OUTD * KPAD) {
        int row = idx / KPAD, col = idx - row * KPAD;
        Wpad[idx] = (col < INFO) ? (__bf16)W_out[row * INFO + col] : (__bf16)0.0f;
    } else {
        int j = idx - OUTD * KPAD;
        if (j < 2 * G4 * HID) {
            const float* src = (j < G4 * HID) ? Whh_f : Whh_b;
            int k = (j < G4 * HID) ? j : j - G4 * HID;
            WhhB[j] = (__bf16)src[k];
        }
    }
}

// K2: persistent BiLSTM recurrence. Block: 16 words x 1 direction, 512 thr (8 waves).
// Wave w owns hidden cols [w*16, w*16+16) for ALL four gates -> local c/h update.
// Bfrag = 4 gates x 4 ksteps = 64 VGPRs/lane; h double-buffered in LDS (1 barrier/step).
__global__ __launch_bounds__(512, 4) void lstm_kernel(
        const int*   __restrict__ char_ids,   // [8192][16] int32
        const float* __restrict__ pre,        // [2][128][512] fp32
        const __bf16* __restrict__ WhhB,      // [2][512][128] bf16 (from prep)
        __bf16* __restrict__ char_feat) {     // [8192][256] bf16
    const int dir = blockIdx.y;
    const int wb  = blockIdx.x * WB;
    const __bf16* Whh = WhhB + dir * G4 * HID;
    const float* preD = pre + dir * 128 * G4;

    const int tid  = threadIdx.x;
    const int wave = tid >> 6;
    const int lane = tid & 63;
    const int col  = lane & 15;
    const int quad = lane >> 4;
    const int jbase = wave * 16;

    __shared__ __bf16 h_lds[2][WB][136];   // 136: 272B row stride, 16B aligned
    __shared__ int    cid_lds[WB][CHAR_LEN];

    if (tid < WB * CHAR_LEN) {
        int w = tid >> 4, t = tid & 15;
        cid_lds[w][t] = char_ids[(wb + w) * CHAR_LEN + t];
    }
    for (int i = tid; i < 2 * WB * 136; i += 512) ((__bf16*)h_lds)[i] = (__bf16)0.0f;

    // Hoist Whh B-fragments: B[k][n]=Whh[row=tt*128+jbase+col][k], k=ks*32+quad*8+j
    bf16x8 Bfrag[4][4];   // [gate][kstep] -> 64 VGPRs
    #pragma unroll
    for (int tt = 0; tt < 4; ++tt) {
        int row = tt * HID + jbase + col;
        #pragma unroll
        for (int ks = 0; ks < 4; ++ks)
            Bfrag[tt][ks] = *(const bf16x8*)(Whh + row * HID + ks * 32 + quad * 8);
    }

    float c[4] = {}, sumh[4] = {};

    __syncthreads();   // cid_lds + h zero-init visible

    // prefetch t=0 input-projection gather (includes both biases)
    f32x4 nxt[4];
    {
        const int tc0 = dir ? (CHAR_LEN - 1) : 0;
        #pragma unroll
        for (int r = 0; r < 4; ++r) {
            const float* p = preD + cid_lds[quad * 4 + r][tc0] * G4 + jbase + col;
            #pragma unroll
            for (int tt = 0; tt < 4; ++tt) nxt[tt][r] = p[tt * HID];
        }
    }

    for (int t = 0; t < CHAR_LEN; ++t) {
        const __bf16 (*hc)[136] = h_lds[t & 1];
        __bf16 (*hn)[136] = h_lds[(t + 1) & 1];

        f32x4 acc[4];
        // ks=0 consumes nxt as accumulator init
        bf16x8 A = *(const bf16x8*)(&hc[col][quad * 8]);
        #pragma unroll
        for (int tt = 0; tt < 4; ++tt)
            acc[tt] = __builtin_amdgcn_mfma_f32_16x16x32_bf16(A, Bfrag[tt][0], nxt[tt], 0, 0, 0);

        // prefetch next timestep's gather (depends only on cid, overlaps MFMA+epilogue)
        if (t + 1 < CHAR_LEN) {
            const int tc = dir ? (CHAR_LEN - 2 - t) : (t + 1);
            #pragma unroll
            for (int r = 0; r < 4; ++r) {
                const float* p = preD + cid_lds[quad * 4 + r][tc] * G4 + jbase + col;
                #pragma unroll
                for (int tt = 0; tt < 4; ++tt) nxt[tt][r] = p[tt * HID];
            }
        }

        #pragma unroll
        for (int ks = 1; ks < 4; ++ks) {
            A = *(const bf16x8*)(&hc[col][ks * 32 + quad * 8]);
            #pragma unroll
            for (int tt = 0; tt < 4; ++tt)
                acc[tt] = __builtin_amdgcn_mfma_f32_16x16x32_bf16(A, Bfrag[tt][ks], acc[tt], 0, 0, 0);
        }

        // gate order i,f,g,o ; C/D layout: word-row = quad*4+r, col = n
        #pragma unroll
        for (int r = 0; r < 4; ++r) {
            float iv = sigmoidf_(acc[0][r]);
            float fv = sigmoidf_(acc[1][r]);
            float gv = tanhf_  (acc[2][r]);
            float ov = sigmoidf_(acc[3][r]);
            float cv = fv * c[r] + iv * gv;
            c[r] = cv;
            float hv = ov * tanhf_(cv);
            sumh[r] += hv;
            hn[quad * 4 + r][jbase + col] = (__bf16)hv;
        }
        __syncthreads();   // hn writes complete before next iter reads; hc reads done before overwrite
    }

    #pragma unroll
    for (int r = 0; r < 4; ++r)
        char_feat[(wb + quad * 4 + r) * 256 + dir * HID + jbase + col] = (__bf16)sumh[r];
}

// K3: out[word][o] = tanh(feat . W_out[o] + b_out[o]); M=32 tile, MFMA over K=576
__global__ __launch_bounds__(256, 4) void out_kernel(
        const int*   __restrict__ word_ids,
        const float* __restrict__ word_table,   // [50000][300] fp32
        const __bf16* __restrict__ char_feat,   // [8192][256] bf16
        const __bf16* __restrict__ Wpad,        // [512][576] bf16
        const float* __restrict__ b_out,        // [512] fp32
        float* __restrict__ out) {              // [8192][512] fp32
    const int wb  = blockIdx.x * WB2;
    const int tid = threadIdx.x;
    const int wave = tid >> 6, lane = tid & 63, col = lane & 15, quad = lane >> 4;

    __shared__ __bf16 feat[WB2][584];   // 1168B row stride, 16B aligned
    __shared__ int wid[WB2];
    if (tid < WB2) wid[tid] = word_ids[wb + tid];
    __syncthreads();
    for (int idx = tid; idx < WB2 * 584; idx += 256) {
        int row = idx / 584, cc = idx - row * 584;
        __bf16 v;
        if (cc < WORD_DIM)  v = (__bf16)word_table[wid[row] * WORD_DIM + cc];
        else if (cc < INFO) v = char_feat[(wb + row) * 256 + (cc - WORD_DIM)];
        else                v = (__bf16)0.0f;
        feat[row][cc] = v;
    }
    __syncthreads();

    f32x4 acc[8][2];
    #pragma unroll
    for (int nt = 0; nt < 8; ++nt)
        #pragma unroll
        for (int mt = 0; mt < 2; ++mt) acc[nt][mt] = (f32x4){0.f, 0.f, 0.f, 0.f};

    for (int kb = 0; kb < KPAD / 32; ++kb) {
        bf16x8 A0 = *(const bf16x8*)(&feat[col][kb * 32 + quad * 8]);
        bf16x8 A1 = *(const bf16x8*)(&feat[16 + col][kb * 32 + quad * 8]);
        #pragma unroll
        for (int nt = 0; nt < 8; ++nt) {
            int n = wave * 128 + nt * 16 + col;
            bf16x8 B = *(const bf16x8*)(Wpad + n * KPAD + kb * 32 + quad * 8);
            acc[nt][0] = __builtin_amdgcn_mfma_f32_16x16x32_bf16(A0, B, acc[nt][0], 0, 0, 0);
            acc[nt][1] = __builtin_amdgcn_mfma_f32_16x16x32_bf16(A1, B, acc[nt][1], 0, 0, 0);
        }
    }

    #pragma unroll
    for (int nt = 0; nt < 8; ++nt) {
        int n = wave * 128 + nt * 16 + col;
        float bo = b_out[n];
        #pragma unroll
        for (int mt = 0; mt < 2; ++mt)
            #pragma unroll
            for (int r = 0; r < 4; ++r) {
                int word = wb + mt * 16 + quad * 4 + r;
                out[word * OUTD + n] = tanhf_(acc[nt][mt][r] + bo);
            }
    }
}

extern "C" void kernel_launch(void* const* d_in, const int* in_sizes, int n_in,
                              void* d_out, int out_size, void* d_ws, size_t ws_size,
                              hipStream_t stream) {
    const int*   word_ids   = (const int*)d_in[0];
    const int*   char_ids   = (const int*)d_in[1];
    const float* word_table = (const float*)d_in[2];
    const float* char_table = (const float*)d_in[3];
    const float* Wih_f = (const float*)d_in[4];
    const float* Whh_f = (const float*)d_in[5];
    const float* bih_f = (const float*)d_in[6];
    const float* bhh_f = (const float*)d_in[7];
    const float* Wih_b = (const float*)d_in[8];
    const float* Whh_b = (const float*)d_in[9];
    const float* bih_b = (const float*)d_in[10];
    const float* bhh_b = (const float*)d_in[11];
    const float* W_out = (const float*)d_in[12];
    const float* b_out = (const float*)d_in[13];

    char* ws = (char*)d_ws;
    float*  pre       = (float*)ws;                         // 2*128*512*4 = 512 KB
    __bf16* WhhB      = (__bf16*)(ws + 524288);             // 2*512*128*2 = 256 KB
    __bf16* Wpad      = (__bf16*)(ws + 524288 + 262144);    // 512*576*2   = 576 KB
    __bf16* char_feat = (__bf16*)(ws + 524288 + 262144 + 589824);  // 8192*256*2 = 4 MB

    prep_kernel<<<(OUTD * KPAD + 2 * G4 * HID + 255) / 256, 256, 0, stream>>>(
        W_out, Whh_f, Whh_b, Wpad, WhhB);
    pre_kernel<<<dim3(128, 2), 256, 0, stream>>>(char_table, Wih_f, bih_f, bhh_f,
                                                 Wih_b, bih_b, bhh_b, pre);
    lstm_kernel<<<dim3(N_WORDS / WB, 2), 512, 0, stream>>>(char_ids, pre, WhhB, char_feat);
    out_kernel<<<N_WORDS / WB2, 256, 0, stream>>>(word_ids, word_table, char_feat, Wpad, b_out,
                                                  (float*)d_out);
}

// Round 4
// 221.585 us; speedup vs baseline: 1.2870x; 1.2811x over previous
//
#include <hip/hip_runtime.h>
#include <hip/hip_bf16.h>

typedef __bf16 bf16x8 __attribute__((ext_vector_type(8)));
typedef float  f32x4  __attribute__((ext_vector_type(4)));

#define N_WORDS   8192
#define CHAR_LEN  16
#define WORD_DIM  300
#define CHAR_DIM  64
#define HID       128
#define G4        512      // 4*HID
#define INFO      556
#define KPAD      576      // 556 padded to 18*32
#define OUTD      512
#define WB        16       // words per lstm block (M tile)
#define L2E       1.4426950408889634f

// sigmoid: rcp(1+exp2(-x*log2e)) ; saturates correctly, 4 VALU
__device__ __forceinline__ float sig_(float x) {
    return __builtin_amdgcn_rcpf(1.0f + __builtin_amdgcn_exp2f(-L2E * x));
}
// tanh: 1 - 2*rcp(1+exp2(2x*log2e)) ; x->+inf: exp=inf,rcp=0 -> 1 ; x->-inf: -1. 5 VALU
__device__ __forceinline__ float tanh_(float x) {
    return 1.0f - 2.0f * __builtin_amdgcn_rcpf(1.0f + __builtin_amdgcn_exp2f((2.0f * L2E) * x));
}

// K1: preT[dir][cid][j][tt] = (char_table[cid] . Wih[row=tt*128+j]) + bih + bhh  (fp32)
// gate-interleaved layout: one f32x4 per (cid, hidden j) = {i,f,g,o}
__global__ void pre_kernel(const float* __restrict__ char_table,
                           const float* __restrict__ Wih_f, const float* __restrict__ bih_f,
                           const float* __restrict__ bhh_f,
                           const float* __restrict__ Wih_b, const float* __restrict__ bih_b,
                           const float* __restrict__ bhh_b,
                           float* __restrict__ preT) {
    const int dir = blockIdx.y;
    const int cid = blockIdx.x;
    const float* Wih = dir ? Wih_b : Wih_f;
    const float* b1  = dir ? bih_b : bih_f;
    const float* b2  = dir ? bhh_b : bhh_f;
    __shared__ float x[CHAR_DIM];
    if (threadIdx.x < CHAR_DIM) x[threadIdx.x] = char_table[cid * CHAR_DIM + threadIdx.x];
    __syncthreads();
    for (int g = threadIdx.x; g < G4; g += 256) {
        const f32x4* w4 = (const f32x4*)(Wih + g * CHAR_DIM);
        const f32x4* x4 = (const f32x4*)x;
        float s = b1[g] + b2[g];
        #pragma unroll
        for (int d = 0; d < CHAR_DIM / 4; ++d) {
            f32x4 wv = w4[d], xv = x4[d];
            s += wv[0]*xv[0] + wv[1]*xv[1] + wv[2]*xv[2] + wv[3]*xv[3];
        }
        int tt = g >> 7, j = g & (HID - 1);
        preT[(dir * 128 + cid) * G4 + j * 4 + tt] = s;
    }
}

// K0: build bf16 Wpad [512][576] (zero tail) and bf16 Whh [2][512][128] from fp32 inputs
__global__ void prep_kernel(const float* __restrict__ W_out,
                            const float* __restrict__ Whh_f, const float* __restrict__ Whh_b,
                            __bf16* __restrict__ Wpad, __bf16* __restrict__ WhhB) {
    int idx = blockIdx.x * 256 + threadIdx.x;
    if (idx < OUTD * KPAD) {
        int row = idx / KPAD, col = idx - row * KPAD;
        Wpad[idx] = (col < INFO) ? (__bf16)W_out[row * INFO + col] : (__bf16)0.0f;
    } else {
        int j = idx - OUTD * KPAD;
        if (j < 2 * G4 * HID) {
            const float* src = (j < G4 * HID) ? Whh_f : Whh_b;
            int k = (j < G4 * HID) ? j : j - G4 * HID;
            WhhB[j] = (__bf16)src[k];
        }
    }
}

// K2: persistent BiLSTM recurrence. Block: 16 words x 1 direction, 512 thr (8 waves).
// Wave w owns hidden cols [w*16, w*16+16) for all four gates -> local c/h update.
__global__ __launch_bounds__(512, 4) void lstm_kernel(
        const int*   __restrict__ char_ids,   // [8192][16] int32
        const float* __restrict__ preT,       // [2][128][128][4] fp32 gate-interleaved
        const __bf16* __restrict__ WhhB,      // [2][512][128] bf16
        __bf16* __restrict__ char_feat) {     // [8192][256] bf16
    const int dir = blockIdx.y;
    const int wb  = blockIdx.x * WB;
    const __bf16* Whh = WhhB + dir * G4 * HID;
    const float* preD = preT + dir * 128 * G4;

    const int tid  = threadIdx.x;
    const int wave = tid >> 6;
    const int lane = tid & 63;
    const int col  = lane & 15;
    const int quad = lane >> 4;
    const int jbase = wave * 16;

    __shared__ __bf16 h_lds[2][WB][136];   // 272B row stride (17x16B units -> balanced b128)
    __shared__ int    cid_lds[WB][CHAR_LEN];

    if (tid < WB * CHAR_LEN) {
        int w = tid >> 4, t = tid & 15;
        cid_lds[w][t] = char_ids[(wb + w) * CHAR_LEN + t];
    }
    for (int i = tid; i < 2 * WB * 136; i += 512) ((__bf16*)h_lds)[i] = (__bf16)0.0f;

    // Hoist Whh B-fragments: B[k][n]=Whh[row=tt*128+jbase+col][k], k=ks*32+quad*8+j
    bf16x8 Bfrag[4][4];   // [gate][kstep]
    #pragma unroll
    for (int tt = 0; tt < 4; ++tt) {
        int row = tt * HID + jbase + col;
        #pragma unroll
        for (int ks = 0; ks < 4; ++ks)
            Bfrag[tt][ks] = *(const bf16x8*)(Whh + row * HID + ks * 32 + quad * 8);
    }

    float c[4] = {}, sumh[4] = {};

    __syncthreads();   // cid_lds + h zero-init visible

    // prefetch t=0 gather: one f32x4 per word-row = {i,f,g,o} at hidden j=jbase+col
    f32x4 nx[4];
    {
        const int tc0 = dir ? (CHAR_LEN - 1) : 0;
        #pragma unroll
        for (int r = 0; r < 4; ++r)
            nx[r] = *(const f32x4*)(preD + cid_lds[quad * 4 + r][tc0] * G4 + (jbase + col) * 4);
    }

    for (int t = 0; t < CHAR_LEN; ++t) {
        const __bf16 (*hc)[136] = h_lds[t & 1];
        __bf16 (*hn)[136] = h_lds[(t + 1) & 1];

        // transpose nx[r][tt] -> acc[tt][r] (MFMA C register order)
        f32x4 acc[4];
        #pragma unroll
        for (int tt = 0; tt < 4; ++tt)
            acc[tt] = (f32x4){nx[0][tt], nx[1][tt], nx[2][tt], nx[3][tt]};

        bf16x8 A = *(const bf16x8*)(&hc[col][quad * 8]);
        #pragma unroll
        for (int tt = 0; tt < 4; ++tt)
            acc[tt] = __builtin_amdgcn_mfma_f32_16x16x32_bf16(A, Bfrag[tt][0], acc[tt], 0, 0, 0);

        // prefetch next timestep's gather (depends only on cid; overlaps MFMA+epilogue)
        if (t + 1 < CHAR_LEN) {
            const int tc = dir ? (CHAR_LEN - 2 - t) : (t + 1);
            #pragma unroll
            for (int r = 0; r < 4; ++r)
                nx[r] = *(const f32x4*)(preD + cid_lds[quad * 4 + r][tc] * G4 + (jbase + col) * 4);
        }

        #pragma unroll
        for (int ks = 1; ks < 4; ++ks) {
            A = *(const bf16x8*)(&hc[col][ks * 32 + quad * 8]);
            #pragma unroll
            for (int tt = 0; tt < 4; ++tt)
                acc[tt] = __builtin_amdgcn_mfma_f32_16x16x32_bf16(A, Bfrag[tt][ks], acc[tt], 0, 0, 0);
        }

        // gate order i,f,g,o ; C/D layout: word-row = quad*4+r, col = n
        #pragma unroll
        for (int r = 0; r < 4; ++r) {
            float iv = sig_(acc[0][r]);
            float fv = sig_(acc[1][r]);
            float gv = tanh_(acc[2][r]);
            float ov = sig_(acc[3][r]);
            float cv = fv * c[r] + iv * gv;
            c[r] = cv;
            float hv = ov * tanh_(cv);
            sumh[r] += hv;
            hn[quad * 4 + r][jbase + col] = (__bf16)hv;
        }
        __syncthreads();
    }

    #pragma unroll
    for (int r = 0; r < 4; ++r)
        char_feat[(wb + quad * 4 + r) * 256 + dir * HID + jbase + col] = (__bf16)sumh[r];
}

// K3: out[word][o] = tanh(feat . W_out[o] + b_out[o]); M=16 tile, MFMA over K=576
__global__ __launch_bounds__(256, 4) void out_kernel(
        const int*   __restrict__ word_ids,
        const float* __restrict__ word_table,   // [50000][300] fp32
        const __bf16* __restrict__ char_feat,   // [8192][256] bf16
        const __bf16* __restrict__ Wpad,        // [512][576] bf16
        const float* __restrict__ b_out,        // [512] fp32
        float* __restrict__ out) {              // [8192][512] fp32
    const int wb  = blockIdx.x * WB;
    const int tid = threadIdx.x;
    const int wave = tid >> 6, lane = tid & 63, col = lane & 15, quad = lane >> 4;

    __shared__ __bf16 feat[WB][584];   // 1168B row stride, 16B aligned
    __shared__ int wid[WB];
    if (tid < WB) wid[tid] = word_ids[wb + tid];
    __syncthreads();
    // word part: 300 = 75 f32x4 chunks per row (rows are 1200B -> 16B aligned)
    for (int idx = tid; idx < WB * 75; idx += 256) {
        int row = idx / 75, ch = idx - row * 75;
        f32x4 v = *(const f32x4*)(word_table + wid[row] * WORD_DIM + ch * 4);
        __bf16* d = &feat[row][ch * 4];
        d[0] = (__bf16)v[0]; d[1] = (__bf16)v[1]; d[2] = (__bf16)v[2]; d[3] = (__bf16)v[3];
    }
    // char part: 256 bf16 = 32 bf16x8 chunks per row
    for (int idx = tid; idx < WB * 32; idx += 256) {
        int row = idx / 32, ch = idx - row * 32;
        bf16x8 v = *(const bf16x8*)(char_feat + (wb + row) * 256 + ch * 8);
        __bf16* d = &feat[row][WORD_DIM + ch * 8];
        #pragma unroll
        for (int e = 0; e < 8; ++e) d[e] = v[e];
    }
    // zero pad 556..583
    for (int idx = tid; idx < WB * 28; idx += 256) {
        int row = idx / 28, cc = idx - row * 28;
        feat[row][INFO + cc] = (__bf16)0.0f;
    }
    __syncthreads();

    f32x4 acc[8];
    #pragma unroll
    for (int nt = 0; nt < 8; ++nt) acc[nt] = (f32x4){0.f, 0.f, 0.f, 0.f};

    for (int kb = 0; kb < KPAD / 32; ++kb) {
        bf16x8 A = *(const bf16x8*)(&feat[col][kb * 32 + quad * 8]);
        #pragma unroll
        for (int nt = 0; nt < 8; ++nt) {
            int n = wave * 128 + nt * 16 + col;
            bf16x8 B = *(const bf16x8*)(Wpad + n * KPAD + kb * 32 + quad * 8);
            acc[nt] = __builtin_amdgcn_mfma_f32_16x16x32_bf16(A, B, acc[nt], 0, 0, 0);
        }
    }

    #pragma unroll
    for (int nt = 0; nt < 8; ++nt) {
        int n = wave * 128 + nt * 16 + col;
        float bo = b_out[n];
        #pragma unroll
        for (int r = 0; r < 4; ++r) {
            int word = wb + quad * 4 + r;
            out[word * OUTD + n] = tanh_(acc[nt][r] + bo);
        }
    }
}

extern "C" void kernel_launch(void* const* d_in, const int* in_sizes, int n_in,
                              void* d_out, int out_size, void* d_ws, size_t ws_size,
                              hipStream_t stream) {
    const int*   word_ids   = (const int*)d_in[0];
    const int*   char_ids   = (const int*)d_in[1];
    const float* word_table = (const float*)d_in[2];
    const float* char_table = (const float*)d_in[3];
    const float* Wih_f = (const float*)d_in[4];
    const float* Whh_f = (const float*)d_in[5];
    const float* bih_f = (const float*)d_in[6];
    const float* bhh_f = (const float*)d_in[7];
    const float* Wih_b = (const float*)d_in[8];
    const float* Whh_b = (const float*)d_in[9];
    const float* bih_b = (const float*)d_in[10];
    const float* bhh_b = (const float*)d_in[11];
    const float* W_out = (const float*)d_in[12];
    const float* b_out = (const float*)d_in[13];

    char* ws = (char*)d_ws;
    float*  preT      = (float*)ws;                         // 2*128*512*4 = 512 KB
    __bf16* WhhB      = (__bf16*)(ws + 524288);             // 2*512*128*2 = 256 KB
    __bf16* Wpad      = (__bf16*)(ws + 524288 + 262144);    // 512*576*2   = 576 KB
    __bf16* char_feat = (__bf16*)(ws + 524288 + 262144 + 589824);  // 8192*256*2 = 4 MB

    prep_kernel<<<(OUTD * KPAD + 2 * G4 * HID + 255) / 256, 256, 0, stream>>>(
        W_out, Whh_f, Whh_b, Wpad, WhhB);
    pre_kernel<<<dim3(128, 2), 256, 0, stream>>>(char_table, Wih_f, bih_f, bhh_f,
                                                 Wih_b, bih_b, bhh_b, preT);
    lstm_kernel<<<dim3(N_WORDS / WB, 2), 512, 0, stream>>>(char_ids, preT, WhhB, char_feat);
    out_kernel<<<N_WORDS / WB, 256, 0, stream>>>(word_ids, word_table, char_feat, Wpad, b_out,
                                                 (float*)d_out);
}